// Round 5
// baseline (709.762 us; speedup 1.0000x reference)
//
#include <hip/hip_runtime.h>
#include <cstdint>
#include <cstddef>
#include <math.h>

// Problem constants (match reference: B,C,N,K = 16,64,2048,20)
#define BB 16
#define CC 64
#define NN 2048
#define KK 20
#define K2 14   // ceil(20*2/3)
#define TQ 16   // queries per block in knn kernel (one per wave)
#define NC 26   // fp32 candidate count (margin over K=20 for refine safety)
#define PDS 2052 // padded pd row stride (floats); 2052%32==4 -> conflict-free C writes

typedef unsigned short ushort_t;
typedef __attribute__((ext_vector_type(8))) short bf16x8;
typedef __attribute__((ext_vector_type(4))) float f32x4;

__device__ inline ushort_t f2bf_rne(float f) {
    uint32_t u = __float_as_uint(f);
    uint32_t r = (u + 0x7FFFu + ((u >> 16) & 1u)) >> 16;
    return (ushort_t)r;
}

// ---------------------------------------------------------------------------
// prep: xt[b][n][c] = x[b][c][n] (fp32), xth/xtl = bf16 hi/lo split of xt
// (for MFMA), plus norms in fp64+fp32.
// ---------------------------------------------------------------------------
__global__ __launch_bounds__(256) void prep_kernel(const float* __restrict__ x,
                                                   float* __restrict__ xt,
                                                   ushort_t* __restrict__ xth,
                                                   ushort_t* __restrict__ xtl,
                                                   float* __restrict__ xxf,
                                                   double* __restrict__ xxd) {
    __shared__ float s_t[64][65];
    int b = blockIdx.x >> 5;
    int n0 = (blockIdx.x & 31) * 64;
    const float* xb = x + (size_t)b * CC * NN;
    int tid = threadIdx.x;
    int cq = tid >> 6;
    int nl = tid & 63;

#pragma unroll
    for (int r = 0; r < 16; ++r) {
        int c = r * 4 + cq;
        s_t[c][nl] = xb[c * NN + n0 + nl];
    }
    __syncthreads();

#pragma unroll
    for (int r = 0; r < 16; ++r) {
        int n = r * 4 + cq;
        float v = s_t[nl][n];
        size_t off = ((size_t)b * NN + n0 + n) * CC + nl;
        xt[off] = v;
        ushort_t h = f2bf_rne(v);
        float hv = __uint_as_float((uint32_t)h << 16);
        xth[off] = h;
        xtl[off] = f2bf_rne(v - hv);
    }

    if (tid < 64) {
        double s = 0.0;
#pragma unroll
        for (int c = 0; c < CC; ++c) {
            double v = (double)s_t[c][tid];
            s += v * v;
        }
        xxd[b * NN + n0 + tid] = s;
        xxf[b * NN + n0 + tid] = (float)s;
    }
}

// ---------------------------------------------------------------------------
// knn v5: 1024 threads = 16 waves; 16 queries/block (one per wave).
// Phase 1: MFMA gram fill. x = h + l (bf16 hi/lo); dot = hh + hl + lh
//   (residual ~2^-17 rel, far below candidate-selection margin).
//   Wave w computes n-tiles w*8..w*8+7 with mfma_f32_16x16x32_bf16,
//   writes s_pd[q][n] = 2*dot - xx_n  (the -xx_q shift is order-preserving
//   per row and dropped). C/D layout: col=lane&15, row=quad*4+reg.
// Phase 2: per-wave register-resident threshold selection (round-4 design):
//   tau = 26th-largest lane-max; survivors compacted, bitonic-sorted
//   (val desc, idx asc); exact iterative fallback if >64 survivors.
// Phase 3: fp64 refine of 26 candidates; 32-lane fp64 bitonic; top-20 out.
// ---------------------------------------------------------------------------
__global__ __launch_bounds__(1024) void knn_kernel(const float* __restrict__ xt,
                                                   const ushort_t* __restrict__ xth,
                                                   const ushort_t* __restrict__ xtl,
                                                   const float* __restrict__ xxf,
                                                   const double* __restrict__ xxd,
                                                   int* __restrict__ idx_ws,
                                                   float* __restrict__ idx_out) {
    __shared__ float s_pd[TQ][PDS];      // 131.3 KB
    __shared__ float s_qf[TQ][CC];       // 4 KB (fp32 queries for refine)
    __shared__ float s_sv[TQ][64];
    __shared__ int   s_si[TQ][64];

    int tid = threadIdx.x;
    int b = blockIdx.x >> 7;                 // 128 blocks/batch
    int nq0 = (blockIdx.x & 127) * TQ;

    {   // stage fp32 query rows (consumed after the barrier)
        int q = tid >> 6, c = tid & 63;
        s_qf[q][c] = xt[((size_t)b * NN + nq0 + q) * CC + c];
    }

    int w = tid >> 6;
    int lane = tid & 63;
    int mrow = lane & 15, quad = lane >> 4;

    // ---- phase 1: MFMA fill ----
    {
        const size_t rowbase = (size_t)b * NN * CC;
        const ushort_t* Ah = xth + rowbase + (size_t)(nq0 + mrow) * CC + quad * 8;
        const ushort_t* Al = xtl + rowbase + (size_t)(nq0 + mrow) * CC + quad * 8;
        bf16x8 ah0 = *(const bf16x8*)(Ah);
        bf16x8 ah1 = *(const bf16x8*)(Ah + 32);
        bf16x8 al0 = *(const bf16x8*)(Al);
        bf16x8 al1 = *(const bf16x8*)(Al + 32);

#pragma unroll
        for (int t = 0; t < 8; ++t) {
            int nt = w * 8 + t;
            int ncol = nt * 16 + mrow;
            const ushort_t* Bh = xth + rowbase + (size_t)ncol * CC + quad * 8;
            const ushort_t* Bl = xtl + rowbase + (size_t)ncol * CC + quad * 8;
            bf16x8 bh0 = *(const bf16x8*)(Bh);
            bf16x8 bh1 = *(const bf16x8*)(Bh + 32);
            bf16x8 bl0 = *(const bf16x8*)(Bl);
            bf16x8 bl1 = *(const bf16x8*)(Bl + 32);

            f32x4 acc = {0.f, 0.f, 0.f, 0.f};
            acc = __builtin_amdgcn_mfma_f32_16x16x32_bf16(ah0, bh0, acc, 0, 0, 0);
            acc = __builtin_amdgcn_mfma_f32_16x16x32_bf16(ah1, bh1, acc, 0, 0, 0);
            acc = __builtin_amdgcn_mfma_f32_16x16x32_bf16(ah0, bl0, acc, 0, 0, 0);
            acc = __builtin_amdgcn_mfma_f32_16x16x32_bf16(ah1, bl1, acc, 0, 0, 0);
            acc = __builtin_amdgcn_mfma_f32_16x16x32_bf16(al0, bh0, acc, 0, 0, 0);
            acc = __builtin_amdgcn_mfma_f32_16x16x32_bf16(al1, bh1, acc, 0, 0, 0);

            float xmv = xxf[b * NN + ncol];
#pragma unroll
            for (int r = 0; r < 4; ++r) {
                int qrow = quad * 4 + r;
                s_pd[qrow][ncol] = 2.f * acc[r] - xmv;
            }
        }
    }
    __syncthreads();

    // ---- phase 2: per-wave selection ----
    const float* pd = s_pd[w];

    float v[32];
#pragma unroll
    for (int r = 0; r < 32; ++r) v[r] = pd[lane + (r << 6)];   // idx = lane+64r

    float lmax = v[0]; int lr = 0;
#pragma unroll
    for (int r = 1; r < 32; ++r)
        if (v[r] > lmax) { lmax = v[r]; lr = r; }              // strict >: lowest idx

    // tau = 26th-largest lane-max (values-only 64-lane bitonic, descending)
    float sv = lmax;
#pragma unroll
    for (int k = 2; k <= 64; k <<= 1) {
#pragma unroll
        for (int j = k >> 1; j > 0; j >>= 1) {
            float o = __shfl_xor(sv, j);
            bool dird = ((lane & k) == 0);
            bool first = ((lane & j) == 0);
            sv = (first == dird) ? fmaxf(sv, o) : fminf(sv, o);
        }
    }
    float tau = __shfl(sv, 25);

    int cnt = 0;
#pragma unroll
    for (int r = 0; r < 32; ++r) cnt += (v[r] >= tau) ? 1 : 0;
    int incl = cnt;
#pragma unroll
    for (int off = 1; off < 64; off <<= 1) {
        int o = __shfl_up(incl, off);
        if (lane >= off) incl += o;
    }
    int S = __shfl(incl, 63);

    float fv = -INFINITY;
    int fi = 0x7fffffff;
    if (S <= 64) {
        int wr = incl - cnt;
#pragma unroll
        for (int r = 0; r < 32; ++r) {
            if (v[r] >= tau) { s_sv[w][wr] = v[r]; s_si[w][wr] = lane + (r << 6); ++wr; }
        }
        if (lane < S) { fv = s_sv[w][lane]; fi = s_si[w][lane]; }
    } else {
        // pathological (mass ties): exact iterative top-26 extraction
        for (int t = 0; t < NC; ++t) {
            float bv = lmax; int bi = lane + (lr << 6);
#pragma unroll
            for (int off = 32; off; off >>= 1) {
                float ov = __shfl_xor(bv, off);
                int oi = __shfl_xor(bi, off);
                if (ov > bv || (ov == bv && oi < bi)) { bv = ov; bi = oi; }
            }
            if (lane == t) { fv = bv; fi = bi; }
            if ((bi & 63) == lane) {
                int rsel = bi >> 6;
#pragma unroll
                for (int r = 0; r < 32; ++r) if (r == rsel) v[r] = -INFINITY;
                lmax = v[0]; lr = 0;
#pragma unroll
                for (int r = 1; r < 32; ++r)
                    if (v[r] > lmax) { lmax = v[r]; lr = r; }
            }
        }
    }

    // 64-lane bitonic sort (fv desc, fi asc) -> lanes 0..25 = top-26
#pragma unroll
    for (int k = 2; k <= 64; k <<= 1) {
#pragma unroll
        for (int j = k >> 1; j > 0; j >>= 1) {
            float ov = __shfl_xor(fv, j);
            int oi = __shfl_xor(fi, j);
            bool dird = ((lane & k) == 0);
            bool first = ((lane & j) == 0);
            bool better = (fv > ov) || (fv == ov && fi < oi);
            if (better != (first == dird)) { fv = ov; fi = oi; }
        }
    }

    // ---- phase 3: fp64 refine ----
    float* s_c = &s_pd[w][0];                 // reuse dead pd row (wave-private)
    int nq = nq0 + w;

#pragma unroll
    for (int t = 0; t < NC; ++t) {
        int cand = __shfl(fi, t);
        s_c[lane * 27 + t] = xt[((size_t)b * NN + cand) * CC + lane]; // lane=channel
    }

    double accd = 0.0;
    for (int c = 0; c < CC; ++c) {
        double qc = (double)s_qf[w][c];                       // broadcast read
        double cd = (double)s_c[c * 27 + lane];               // conflict-free
        accd = fma(qc, cd, accd);
    }

    double val = -INFINITY;
    int idxq = 0x7fffffff;
    if (lane < NC) {
        val = 2.0 * accd - xxd[b * NN + nq] - xxd[b * NN + fi];
        idxq = fi;
    }

    // 32-lane fp64 bitonic (val desc, idx asc)
#pragma unroll
    for (int k = 2; k <= 32; k <<= 1) {
#pragma unroll
        for (int j = k >> 1; j > 0; j >>= 1) {
            double ov = __shfl_xor(val, j, 32);
            int oi = __shfl_xor(idxq, j, 32);
            bool dird = ((lane & k) == 0);
            bool first = ((lane & j) == 0);
            bool better = (val > ov) || (val == ov && idxq < oi);
            if (better != (first == dird)) { val = ov; idxq = oi; }
        }
    }

    if (lane < KK) {
        size_t obase = ((size_t)b * NN + nq) * KK;
        idx_ws[obase + lane] = idxq;
        idx_out[obase + lane] = (float)(idxq + b * NN);
    }
}

// ---------------------------------------------------------------------------
// x1: mean of top-14 of 20 gathered neighbor values, written channel-major
// as x1t[b][c][n]. (sum20 - six minima)/14, order-independent.
// ---------------------------------------------------------------------------
__global__ __launch_bounds__(256) void x1_kernel(const float* __restrict__ xt,
                                                 const int* __restrict__ idx_ws,
                                                 float* __restrict__ x1t) {
    __shared__ int s_idx[16][KK];
    __shared__ float s_out[64][17];
    int tid = threadIdx.x;
    int b = blockIdx.x >> 7;
    int n0 = (blockIdx.x & 127) * 16;
    const float* xtb = xt + (size_t)b * NN * CC;

    for (int i = tid; i < 16 * KK; i += 256)
        s_idx[i / KK][i % KK] = idx_ws[((size_t)b * NN + n0) * KK + i];
    __syncthreads();

    int pl = tid >> 6, c = tid & 63;
#pragma unroll
    for (int it = 0; it < 4; ++it) {
        int nl = it * 4 + pl;
        float vals[KK];
        float sum = 0.f;
#pragma unroll
        for (int j = 0; j < KK; ++j) {
            vals[j] = xtb[(size_t)s_idx[nl][j] * CC + c];
            sum += vals[j];
        }
#pragma unroll
        for (int t = 0; t < KK - K2; ++t) {
            float worst = INFINITY;
            int wj = 0;
#pragma unroll
            for (int j = 0; j < KK; ++j)
                if (vals[j] < worst) { worst = vals[j]; wj = j; }
            sum -= worst;
            vals[wj] = INFINITY;
        }
        s_out[c][nl] = sum / (float)K2;
    }
    __syncthreads();

    int cw = tid >> 2, nw = (tid & 3) * 4;
    float4 v = make_float4(s_out[cw][nw], s_out[cw][nw + 1],
                           s_out[cw][nw + 2], s_out[cw][nw + 3]);
    *(float4*)(&x1t[((size_t)b * CC + cw) * NN + n0 + nw]) = v;
}

// ---------------------------------------------------------------------------
// feat: float4-vectorized. feature[b,ch,n,j]:
//   ch <  64: x1t[b,ch,idx[b,n,j]] - x[b,ch,n]
//   ch >= 64: x[b,ch-64,n]
// ---------------------------------------------------------------------------
__global__ __launch_bounds__(256) void feat_kernel(const float* __restrict__ x,
                                                   const float* __restrict__ x1t,
                                                   const int* __restrict__ idx_ws,
                                                   float* __restrict__ out) {
    int bc = blockIdx.x;
    int b = bc >> 7, ch = bc & 127;
    const float* xb = x + (size_t)b * CC * NN;
    float* o = out + (size_t)bc * NN * KK;
    const int* idxb = idx_ws + (size_t)b * NN * KK;

    if (ch < CC) {
        const float* row = x1t + ((size_t)b * CC + ch) * NN;
        const float* xr = xb + ch * NN;
        for (int it = 0; it < 40; ++it) {
            unsigned e = (it * 256 + threadIdx.x) * 4;
            int4 id4 = *(const int4*)(idxb + e);
            float4 o4;
            o4.x = row[id4.x] - xr[(e    ) / KK];
            o4.y = row[id4.y] - xr[(e + 1) / KK];
            o4.z = row[id4.z] - xr[(e + 2) / KK];
            o4.w = row[id4.w] - xr[(e + 3) / KK];
            *(float4*)(o + e) = o4;
        }
    } else {
        const float* xr = xb + (ch - CC) * NN;
        for (int it = 0; it < 40; ++it) {
            unsigned e = (it * 256 + threadIdx.x) * 4;
            float4 o4;
            o4.x = xr[(e    ) / KK];
            o4.y = xr[(e + 1) / KK];
            o4.z = xr[(e + 2) / KK];
            o4.w = xr[(e + 3) / KK];
            *(float4*)(o + e) = o4;
        }
    }
}

// ---------------------------------------------------------------------------
extern "C" void kernel_launch(void* const* d_in, const int* in_sizes, int n_in,
                              void* d_out, int out_size, void* d_ws, size_t ws_size,
                              hipStream_t stream) {
    const float* x = (const float*)d_in[0];   // (B, C, N) fp32
    float* out = (float*)d_out;

    char* ws = (char*)d_ws;
    float* xt      = (float*)ws;                                // B*N*C fp32 (8 MB)
    float* x1t     = (float*)(ws + (size_t)8388608);            // B*C*N fp32 (8 MB)
    double* xxd    = (double*)(ws + (size_t)16777216);          // B*N (256 KB)
    float* xxf     = (float*)(ws + (size_t)17039360);           // B*N (128 KB)
    int* idx_ws    = (int*)(ws + (size_t)17170432);             // B*N*K (2.6 MB)
    ushort_t* xth  = (ushort_t*)(ws + (size_t)20971520);        // B*N*C bf16 (4 MB)
    ushort_t* xtl  = (ushort_t*)(ws + (size_t)25165824);        // B*N*C bf16 (4 MB)

    float* idx_out = out + (size_t)BB * 2 * CC * NN * KK;       // idx_flat tail

    prep_kernel<<<BB * (NN / 64), 256, 0, stream>>>(x, xt, xth, xtl, xxf, xxd);
    knn_kernel<<<BB * (NN / TQ), 1024, 0, stream>>>(xt, xth, xtl, xxf, xxd, idx_ws, idx_out);
    x1_kernel<<<BB * (NN / 16), 256, 0, stream>>>(xt, idx_ws, x1t);
    feat_kernel<<<BB * 2 * CC, 256, 0, stream>>>(x, x1t, idx_ws, out);
}